// Round 3
// baseline (291.080 us; speedup 1.0000x reference)
//
#include <hip/hip_runtime.h>
#include <stdint.h>

// Problem constants (fixed by the reference module).
#define N_NODES 100000
#define F_IN    512
#define F_OUT   128
#define BROWS   128                                   // rows per bucket (binning granularity)
#define NBKT    ((N_NODES + BROWS - 1) / BROWS)       // 782
#define CAP     2560                                  // bucket capacity (avg 2048 + ~11 sigma)
#define EPB     4096                                  // edges per LDS sort chunk
#define CHUNKS  4
#define BLKE    (EPB * CHUNKS)                        // 16384 edges per binning block
#define GSTR    16                                    // counter stride (64B): line-private atomics
#define BR2     64                                    // rows per STAGE block (half bucket)
#define SCAP    1536                                  // per-half-bucket CSR capacity

typedef unsigned short     u16;
typedef unsigned int       u32;
typedef unsigned long long u64;
typedef long long          i64;

__device__ __forceinline__ float b2f(u16 u) {
    union { u32 i; float f; } x; x.i = ((u32)u) << 16; return x.f;
}
__device__ __forceinline__ u16 f2b(float f) {
    u32 i = __float_as_uint(f);
    return (u16)((i + 0x7fffu + ((i >> 16) & 1u)) >> 16);   // round-nearest-even
}
__device__ __forceinline__ float blo(u32 u) { return __uint_as_float(u << 16); }
__device__ __forceinline__ float bhi(u32 u) { return __uint_as_float(u & 0xFFFF0000u); }
__device__ __forceinline__ int ld_idx(const void* p, int i, int w64) {
    return w64 ? (int)((const i64*)p)[i] : ((const int*)p)[i];
}
__device__ __forceinline__ u16 ld_val_bf(const void* p, int i, int f32) {
    return f32 ? f2b(((const float*)p)[i]) : ((const u16*)p)[i];
}

// 782-bucket exclusive scan: 4 buckets/thread + wave shfl + 4-wave combine.
// On exit: lbase[b] = exclusive prefix, hist[b] = same (reused as place cursor).
__device__ __forceinline__ void scan782(int* hist, int* lbase, int* wtot, int t) {
    int lane = t & 63, wv = t >> 6;
    int b0 = t * 4;
    int c0 = (b0 + 0 < NBKT) ? hist[b0 + 0] : 0;
    int c1 = (b0 + 1 < NBKT) ? hist[b0 + 1] : 0;
    int c2 = (b0 + 2 < NBKT) ? hist[b0 + 2] : 0;
    int c3 = (b0 + 3 < NBKT) ? hist[b0 + 3] : 0;
    int s = c0 + c1 + c2 + c3;
    int v = s;
    #pragma unroll
    for (int off = 1; off < 64; off <<= 1) {
        int u = __shfl_up(v, off);
        if (lane >= off) v += u;
    }
    if (lane == 63) wtot[wv] = v;
    __syncthreads();
    int woff = 0;
    #pragma unroll
    for (int w = 0; w < 4; ++w) if (w < wv) woff += wtot[w];
    int run = woff + v - s;
    int cc[4] = {c0, c1, c2, c3};
    #pragma unroll
    for (int k = 0; k < 4; ++k) {
        int bb = b0 + k;
        if (bb < NBKT) { lbase[bb] = run; hist[bb] = run; run += cc[k]; }
    }
}

// ---------------------------------------------------------------- dtype sniff + cursor zeroing
// flags[0]=floats are fp32; flags[1]=adj_indices int64; flags[2]=feat idx int64.
__global__ void sniff_k(const u16* __restrict__ w, const u32* __restrict__ adj,
                        const u32* __restrict__ frows, int* __restrict__ flags,
                        int* __restrict__ gcurF, int* __restrict__ gcurA) {
    int t = threadIdx.x;                          // blockDim = 1024
    if (t < 64) {
        int lane = t;
        u32 e0 = (w[lane]      >> 7) & 0xFF;      // bf16 xavier: exp <= 0x7B always
        u32 e1 = (w[64 + lane] >> 7) & 0xFF;
        u64 bad = __ballot((e0 > 0x7B) || (e1 > 0x7B));
        u64 za = __ballot(adj[2 * lane + 1] == 0u);   // int64 ids: odd words are 0
        u64 zf = __ballot(frows[2 * lane + 1] == 0u);
        if (lane == 0) {
            flags[0] = (bad != 0);
            flags[1] = (__popcll(za) >= 32);
            flags[2] = (__popcll(zf) >= 32);
        }
    }
    for (int i = t; i < NBKT * GSTR; i += 1024) { gcurF[i] = 0; gcurA[i] = 0; }
}

// ---------------------------------------------------------------- fused binning (feat + adj)
// Each block owns BLKE=16384 edges: one total histogram -> ONE global atomic per
// (block,bucket) -> 4 sequential in-LDS counting-sort chunks with run-coalesced
// write-out. Counters are 64B-strided so each has a private cache line.
// blocks [0, nFb): feat edges -> 4B payload = val16<<16 | rlocal7<<9 | col9
// blocks [nFb, nFb+nAb): adj edges -> 8B payload = val16<<24 | rlocal7<<17 | col17
__global__ __launch_bounds__(256) void binFA_k(
        const void* __restrict__ frows, const void* __restrict__ fcols,
        const void* __restrict__ fvals, int M, int nFb,
        const void* __restrict__ adjbase, const void* __restrict__ avals, int E,
        const int* __restrict__ flags,
        int* __restrict__ gcurF, int* __restrict__ gcurA,
        u32* __restrict__ fbkt, u64* __restrict__ abkt) {
    __shared__ u64 sortA[EPB];      // 32 KB (feat branch reuses as u32[EPB])
    __shared__ u16 sbkt[EPB];       // 8 KB  bucket id per sorted slot
    __shared__ int hist[NBKT];      // per-chunk counts -> placement cursor
    __shared__ int lbase[NBKT];     // per-chunk local exclusive prefix
    __shared__ int gcur_l[NBKT];    // block total hist -> global write cursor
    __shared__ int wtot[4];
    int t = threadIdx.x;
    for (int i = t; i < NBKT; i += 256) gcur_l[i] = 0;
    __syncthreads();
    int f32 = flags[0];

    if ((int)blockIdx.x < nFb) {
        // ---------------- feat branch ----------------
        int f64 = flags[2];
        int start = blockIdx.x * BLKE;
        int end = min(start + BLKE, M);
        // Phase A: block-total histogram (8-deep load batches)
        {
            int i = start + t;
            while (i + 256 * 7 < end) {
                int r[8];
                #pragma unroll
                for (int k = 0; k < 8; ++k) r[k] = ld_idx(frows, i + 256 * k, f64);
                #pragma unroll
                for (int k = 0; k < 8; ++k) atomicAdd(&gcur_l[r[k] >> 7], 1);
                i += 2048;
            }
            for (; i < end; i += 256) atomicAdd(&gcur_l[ld_idx(frows, i, f64) >> 7], 1);
        }
        __syncthreads();
        // Phase B: ONE global atomic per nonzero bucket, line-private counters
        {
            int b0 = t * 4;
            #pragma unroll
            for (int k = 0; k < 4; ++k) {
                int bb = b0 + k;
                if (bb < NBKT) {
                    int tot = gcur_l[bb];
                    gcur_l[bb] = tot ? atomicAdd(&gcurF[bb * GSTR], tot) : 0;
                }
            }
        }
        __syncthreads();
        // Phase C: per-chunk counting sort + run-coalesced write-out
        u32* sortF = (u32*)sortA;
        for (int c = 0; c < CHUNKS; ++c) {
            int cs = start + c * EPB;
            if (cs >= end) break;                 // block-uniform
            int ce = min(cs + EPB, end);
            int nc = ce - cs;
            for (int i = t; i < NBKT; i += 256) hist[i] = 0;
            __syncthreads();
            {   // chunk histogram (L2-hot re-read)
                int i = cs + t;
                while (i + 256 * 7 < ce) {
                    int r[8];
                    #pragma unroll
                    for (int k = 0; k < 8; ++k) r[k] = ld_idx(frows, i + 256 * k, f64);
                    #pragma unroll
                    for (int k = 0; k < 8; ++k) atomicAdd(&hist[r[k] >> 7], 1);
                    i += 2048;
                }
                for (; i < ce; i += 256) atomicAdd(&hist[ld_idx(frows, i, f64) >> 7], 1);
            }
            __syncthreads();
            scan782(hist, lbase, wtot, t);
            __syncthreads();
            {   // rank-place into LDS in bucket order
                int i = cs + t;
                while (i + 256 * 7 < ce) {
                    int r[8], cc[8]; u32 vv[8];
                    #pragma unroll
                    for (int k = 0; k < 8; ++k) {
                        r[k] = ld_idx(frows, i + 256 * k, f64);
                        cc[k] = ld_idx(fcols, i + 256 * k, f64);
                        vv[k] = ld_val_bf(fvals, i + 256 * k, f32);
                    }
                    #pragma unroll
                    for (int k = 0; k < 8; ++k) {
                        int b = r[k] >> 7;
                        int pos = atomicAdd(&hist[b], 1);
                        sortF[pos] = (vv[k] << 16) | ((u32)(r[k] & 127) << 9) | (u32)cc[k];
                        sbkt[pos] = (u16)b;
                    }
                    i += 2048;
                }
                for (; i < ce; i += 256) {
                    int r = ld_idx(frows, i, f64), cc = ld_idx(fcols, i, f64);
                    u32 vv = ld_val_bf(fvals, i, f32);
                    int b = r >> 7;
                    int pos = atomicAdd(&hist[b], 1);
                    sortF[pos] = (vv << 16) | ((u32)(r & 127) << 9) | (u32)cc;
                    sbkt[pos] = (u16)b;
                }
            }
            __syncthreads();
            for (int i = t; i < nc; i += 256) {   // run-coalesced write-out
                int b = sbkt[i];
                int pos = gcur_l[b] + (i - lbase[b]);
                if (pos < CAP)                     // overflow drops loudly, never stomps
                    fbkt[(size_t)b * CAP + pos] = sortF[i];
            }
            __syncthreads();
            for (int bb = t; bb < NBKT; bb += 256) gcur_l[bb] += hist[bb] - lbase[bb];
            __syncthreads();
        }
    } else {
        // ---------------- adj branch ----------------
        int a64 = flags[1];
        const void* acols = a64 ? (const void*)((const i64*)adjbase + E)
                                : (const void*)((const int*)adjbase + E);
        int start = ((int)blockIdx.x - nFb) * BLKE;
        int end = min(start + BLKE, E);
        {
            int i = start + t;
            while (i + 256 * 7 < end) {
                int r[8];
                #pragma unroll
                for (int k = 0; k < 8; ++k) r[k] = ld_idx(adjbase, i + 256 * k, a64);
                #pragma unroll
                for (int k = 0; k < 8; ++k) atomicAdd(&gcur_l[r[k] >> 7], 1);
                i += 2048;
            }
            for (; i < end; i += 256) atomicAdd(&gcur_l[ld_idx(adjbase, i, a64) >> 7], 1);
        }
        __syncthreads();
        {
            int b0 = t * 4;
            #pragma unroll
            for (int k = 0; k < 4; ++k) {
                int bb = b0 + k;
                if (bb < NBKT) {
                    int tot = gcur_l[bb];
                    gcur_l[bb] = tot ? atomicAdd(&gcurA[bb * GSTR], tot) : 0;
                }
            }
        }
        __syncthreads();
        for (int c = 0; c < CHUNKS; ++c) {
            int cs = start + c * EPB;
            if (cs >= end) break;
            int ce = min(cs + EPB, end);
            int nc = ce - cs;
            for (int i = t; i < NBKT; i += 256) hist[i] = 0;
            __syncthreads();
            {
                int i = cs + t;
                while (i + 256 * 7 < ce) {
                    int r[8];
                    #pragma unroll
                    for (int k = 0; k < 8; ++k) r[k] = ld_idx(adjbase, i + 256 * k, a64);
                    #pragma unroll
                    for (int k = 0; k < 8; ++k) atomicAdd(&hist[r[k] >> 7], 1);
                    i += 2048;
                }
                for (; i < ce; i += 256) atomicAdd(&hist[ld_idx(adjbase, i, a64) >> 7], 1);
            }
            __syncthreads();
            scan782(hist, lbase, wtot, t);
            __syncthreads();
            {
                int i = cs + t;
                while (i + 256 * 7 < ce) {
                    int r[8], cc[8]; u32 vv[8];
                    #pragma unroll
                    for (int k = 0; k < 8; ++k) {
                        r[k] = ld_idx(adjbase, i + 256 * k, a64);
                        cc[k] = ld_idx(acols, i + 256 * k, a64);
                        vv[k] = ld_val_bf(avals, i + 256 * k, f32);
                    }
                    #pragma unroll
                    for (int k = 0; k < 8; ++k) {
                        int b = r[k] >> 7;
                        int pos = atomicAdd(&hist[b], 1);
                        sortA[pos] = ((u64)vv[k] << 24) | ((u64)(r[k] & 127) << 17) | (u64)(u32)cc[k];
                        sbkt[pos] = (u16)b;
                    }
                    i += 2048;
                }
                for (; i < ce; i += 256) {
                    int r = ld_idx(adjbase, i, a64), cc = ld_idx(acols, i, a64);
                    u64 vv = ld_val_bf(avals, i, f32);
                    int b = r >> 7;
                    int pos = atomicAdd(&hist[b], 1);
                    sortA[pos] = (vv << 24) | ((u64)(r & 127) << 17) | (u64)(u32)cc;
                    sbkt[pos] = (u16)b;
                }
            }
            __syncthreads();
            for (int i = t; i < nc; i += 256) {
                int b = sbkt[i];
                int pos = gcur_l[b] + (i - lbase[b]);
                if (pos < CAP)
                    abkt[(size_t)b * CAP + pos] = sortA[i];
            }
            __syncthreads();
            for (int bb = t; bb < NBKT; bb += 256) gcur_l[bb] += hist[bb] - lbase[bb];
            __syncthreads();
        }
    }
}

// ---------------------------------------------------------------- stage 1: base = S_feat @ W
// Block = half bucket (64 rows), 256 threads. CSR build: filtered histogram +
// wave-level shfl scan + rank-place. Compute: 16-lane row-groups — each lane
// owns 8 of 128 cols (one dwordx4 of a W row); one wave instruction gathers
// 4 full W rows; 4-deep batch => 16 nnz in flight per wave.
__global__ __launch_bounds__(256, 8) void stage1_k(const int* __restrict__ cnt,
        const u32* __restrict__ bkts, const void* __restrict__ W,
        const int* __restrict__ flags, u16* __restrict__ base) {
    __shared__ u32 csr[SCAP];                 // 6 KB
    __shared__ int hcnt[BR2];
    __shared__ int roff[BR2 + 1];
    __shared__ int cur[BR2];
    int t = threadIdx.x;
    int b = blockIdx.x >> 1;
    int half = blockIdx.x & 1;
    int n = cnt[b * GSTR]; if (n > CAP) n = CAP;
    const u32* ed = bkts + (size_t)b * CAP;
    if (t < BR2) hcnt[t] = 0;
    __syncthreads();
    for (int i = t; i < n; i += 256) {
        int rl = (ed[i] >> 9) & 0x7F;
        if ((rl >> 6) == half) atomicAdd(&hcnt[rl & 63], 1);
    }
    __syncthreads();
    if (t < 64) {                              // wave-0 inclusive shfl scan, no barriers
        int h = hcnt[t];
        int v = h;
        #pragma unroll
        for (int off = 1; off < 64; off <<= 1) {
            int u = __shfl_up(v, off);
            if (t >= off) v += u;
        }
        roff[t + 1] = v;
        cur[t] = v - h;
        if (t == 0) roff[0] = 0;
    }
    __syncthreads();
    for (int i = t; i < n; i += 256) {         // rank-place into LDS CSR
        u32 p = ed[i];
        int rl = (p >> 9) & 0x7F;
        if ((rl >> 6) == half) {
            int pos = atomicAdd(&cur[rl & 63], 1);
            if (pos < SCAP) csr[pos] = p;
        }
    }
    __syncthreads();
    int wave = t >> 6, lane = t & 63, g = lane >> 4, l16 = lane & 15;
    int f32 = flags[0];
    #pragma unroll
    for (int set = 0; set < 4; ++set) {
        int row = set * 16 + wave * 4 + g;     // 4 waves x 4 groups = 16 rows in parallel
        int s = roff[row], e = roff[row + 1];
        if (s > SCAP) s = SCAP;
        if (e > SCAP) e = SCAP;
        float a[8] = {0.f, 0.f, 0.f, 0.f, 0.f, 0.f, 0.f, 0.f};
        if (f32) {
            const float* Wf = (const float*)W;
            for (int j0 = s; j0 < e; j0 += 4) {
                u32 p[4]; float4 qa[4], qb[4];
                #pragma unroll
                for (int k = 0; k < 4; ++k) { int jk = j0 + k; p[k] = csr[jk < e ? jk : e - 1]; }
                #pragma unroll
                for (int k = 0; k < 4; ++k) {
                    const float* wp = Wf + (size_t)(p[k] & 0x1FF) * F_OUT + l16 * 8;
                    qa[k] = *(const float4*)wp;
                    qb[k] = *(const float4*)(wp + 4);
                }
                #pragma unroll
                for (int k = 0; k < 4; ++k) {
                    float v = (j0 + k < e) ? b2f((u16)(p[k] >> 16)) : 0.f;
                    a[0] += v * qa[k].x; a[1] += v * qa[k].y;
                    a[2] += v * qa[k].z; a[3] += v * qa[k].w;
                    a[4] += v * qb[k].x; a[5] += v * qb[k].y;
                    a[6] += v * qb[k].z; a[7] += v * qb[k].w;
                }
            }
        } else {
            const u16* Wb = (const u16*)W;
            for (int j0 = s; j0 < e; j0 += 4) {
                u32 p[4]; uint4 q[4];
                #pragma unroll
                for (int k = 0; k < 4; ++k) { int jk = j0 + k; p[k] = csr[jk < e ? jk : e - 1]; }
                #pragma unroll
                for (int k = 0; k < 4; ++k)
                    q[k] = *(const uint4*)(Wb + (size_t)(p[k] & 0x1FF) * F_OUT + l16 * 8);
                #pragma unroll
                for (int k = 0; k < 4; ++k) {
                    float v = (j0 + k < e) ? b2f((u16)(p[k] >> 16)) : 0.f;
                    a[0] += v * blo(q[k].x); a[1] += v * bhi(q[k].x);
                    a[2] += v * blo(q[k].y); a[3] += v * bhi(q[k].y);
                    a[4] += v * blo(q[k].z); a[5] += v * bhi(q[k].z);
                    a[6] += v * blo(q[k].w); a[7] += v * bhi(q[k].w);
                }
            }
        }
        int gr = b * BROWS + half * BR2 + row;
        if (gr < N_NODES) {
            uint4 o;
            o.x = (u32)f2b(a[0]) | ((u32)f2b(a[1]) << 16);
            o.y = (u32)f2b(a[2]) | ((u32)f2b(a[3]) << 16);
            o.z = (u32)f2b(a[4]) | ((u32)f2b(a[5]) << 16);
            o.w = (u32)f2b(a[6]) | ((u32)f2b(a[7]) << 16);
            *(uint4*)(base + (size_t)gr * F_OUT + l16 * 8) = o;
        }
    }
}

// ---------------------------------------------------------------- stage 2: out = A_hat @ base
// Same structure; gathers are 256B base rows (bf16), one dwordx4 per lane.
__global__ __launch_bounds__(256, 8) void stage2_k(const int* __restrict__ cnt,
        const u64* __restrict__ bkts, const u16* __restrict__ base,
        const int* __restrict__ flags, void* __restrict__ out) {
    __shared__ u64 csr[SCAP];                 // 12 KB
    __shared__ int hcnt[BR2];
    __shared__ int roff[BR2 + 1];
    __shared__ int cur[BR2];
    int t = threadIdx.x;
    int b = blockIdx.x >> 1;
    int half = blockIdx.x & 1;
    int n = cnt[b * GSTR]; if (n > CAP) n = CAP;
    const u64* ed = bkts + (size_t)b * CAP;
    if (t < BR2) hcnt[t] = 0;
    __syncthreads();
    for (int i = t; i < n; i += 256) {
        int rl = (int)((ed[i] >> 17) & 0x7F);
        if ((rl >> 6) == half) atomicAdd(&hcnt[rl & 63], 1);
    }
    __syncthreads();
    if (t < 64) {
        int h = hcnt[t];
        int v = h;
        #pragma unroll
        for (int off = 1; off < 64; off <<= 1) {
            int u = __shfl_up(v, off);
            if (t >= off) v += u;
        }
        roff[t + 1] = v;
        cur[t] = v - h;
        if (t == 0) roff[0] = 0;
    }
    __syncthreads();
    for (int i = t; i < n; i += 256) {
        u64 p = ed[i];
        int rl = (int)((p >> 17) & 0x7F);
        if ((rl >> 6) == half) {
            int pos = atomicAdd(&cur[rl & 63], 1);
            if (pos < SCAP) csr[pos] = p;
        }
    }
    __syncthreads();
    int wave = t >> 6, lane = t & 63, g = lane >> 4, l16 = lane & 15;
    int f32o = flags[0];
    #pragma unroll
    for (int set = 0; set < 4; ++set) {
        int row = set * 16 + wave * 4 + g;
        int s = roff[row], e = roff[row + 1];
        if (s > SCAP) s = SCAP;
        if (e > SCAP) e = SCAP;
        float a[8] = {0.f, 0.f, 0.f, 0.f, 0.f, 0.f, 0.f, 0.f};
        for (int j0 = s; j0 < e; j0 += 4) {
            u64 p[4]; uint4 q[4];
            #pragma unroll
            for (int k = 0; k < 4; ++k) { int jk = j0 + k; p[k] = csr[jk < e ? jk : e - 1]; }
            #pragma unroll
            for (int k = 0; k < 4; ++k)
                q[k] = *(const uint4*)(base + (size_t)(u32)(p[k] & 0x1FFFF) * F_OUT + l16 * 8);
            #pragma unroll
            for (int k = 0; k < 4; ++k) {
                float v = (j0 + k < e) ? b2f((u16)(p[k] >> 24)) : 0.f;
                a[0] += v * blo(q[k].x); a[1] += v * bhi(q[k].x);
                a[2] += v * blo(q[k].y); a[3] += v * bhi(q[k].y);
                a[4] += v * blo(q[k].z); a[5] += v * bhi(q[k].z);
                a[6] += v * blo(q[k].w); a[7] += v * bhi(q[k].w);
            }
        }
        int gr = b * BROWS + half * BR2 + row;
        if (gr < N_NODES) {
            if (f32o) {
                float* op = (float*)out + (size_t)gr * F_OUT + l16 * 8;
                float4 o0, o1;
                o0.x = a[0]; o0.y = a[1]; o0.z = a[2]; o0.w = a[3];
                o1.x = a[4]; o1.y = a[5]; o1.z = a[6]; o1.w = a[7];
                *(float4*)op = o0;
                *(float4*)(op + 4) = o1;
            } else {
                uint4 o;
                o.x = (u32)f2b(a[0]) | ((u32)f2b(a[1]) << 16);
                o.y = (u32)f2b(a[2]) | ((u32)f2b(a[3]) << 16);
                o.z = (u32)f2b(a[4]) | ((u32)f2b(a[5]) << 16);
                o.w = (u32)f2b(a[6]) | ((u32)f2b(a[7]) << 16);
                *(uint4*)((u16*)out + (size_t)gr * F_OUT + l16 * 8) = o;
            }
        }
    }
}

extern "C" void kernel_launch(void* const* d_in, const int* in_sizes, int n_in,
                              void* d_out, int out_size, void* d_ws, size_t ws_size,
                              hipStream_t stream) {
    const void* adj_idx   = d_in[0];   // [2,E]: rows then cols
    const void* adj_vals  = d_in[1];
    const void* feat_rows = d_in[2];
    const void* feat_cols = d_in[3];
    const void* feat_vals = d_in[4];
    const void* weight    = d_in[5];

    const int E = in_sizes[0] / 2;
    const int M = in_sizes[2];

    // ---- workspace layout (256B-aligned), ~50 MB ----
    char* ws = (char*)d_ws;
    size_t o = 0;
    auto alloc = [&](size_t b) { size_t r = o; o += (b + 255) & ~(size_t)255; return r; };
    int* gcurF = (int*)(ws + alloc((size_t)NBKT * GSTR * 4));    // 50 KB (line-strided)
    int* gcurA = (int*)(ws + alloc((size_t)NBKT * GSTR * 4));    // 50 KB
    int* flags = (int*)(ws + alloc(4 * 4));
    u32* fbkt  = (u32*)(ws + alloc((size_t)NBKT * CAP * 4)); // 8.0 MB
    u64* abkt  = (u64*)(ws + alloc((size_t)NBKT * CAP * 8)); // 16.0 MB
    u16* base  = (u16*)(ws + alloc((size_t)N_NODES * F_OUT * 2)); // 25.6 MB
    (void)ws_size;

    const int nFb = (M + BLKE - 1) / BLKE;   // 98
    const int nAb = (E + BLKE - 1) / BLKE;   // 98

    sniff_k<<<1, 1024, 0, stream>>>((const u16*)weight, (const u32*)adj_idx,
                                    (const u32*)feat_rows, flags, gcurF, gcurA);
    binFA_k<<<nFb + nAb, 256, 0, stream>>>(feat_rows, feat_cols, feat_vals, M, nFb,
                                           adj_idx, adj_vals, E,
                                           flags, gcurF, gcurA, fbkt, abkt);
    stage1_k<<<2 * NBKT, 256, 0, stream>>>(gcurF, fbkt, weight, flags, base);
    stage2_k<<<2 * NBKT, 256, 0, stream>>>(gcurA, abkt, base, flags, d_out);
}

// Round 5
// 262.778 us; speedup vs baseline: 1.1077x; 1.1077x over previous
//
#include <hip/hip_runtime.h>
#include <stdint.h>

// Problem constants (fixed by the reference module).
#define N_NODES 100000
#define F_IN    512
#define F_OUT   128
#define BROWS   128                                   // rows per bucket
#define NBKT    ((N_NODES + BROWS - 1) / BROWS)       // 782
#define CAP     2560                                  // bucket capacity (avg 2048 + ~11 sigma)
#define EPB     2048                                  // edges per bin block (512 thr x 4-edge groups)

typedef unsigned short     u16;
typedef unsigned int       u32;
typedef unsigned long long u64;
typedef long long          i64;

__device__ __forceinline__ float b2f(u16 u) {
    union { u32 i; float f; } x; x.i = ((u32)u) << 16; return x.f;
}
__device__ __forceinline__ u16 f2b(float f) {
    u32 i = __float_as_uint(f);
    return (u16)((i + 0x7fffu + ((i >> 16) & 1u)) >> 16);   // round-nearest-even
}
__device__ __forceinline__ float blo(u32 u) { return __uint_as_float(u << 16); }
__device__ __forceinline__ float bhi(u32 u) { return __uint_as_float(u & 0xFFFF0000u); }
__device__ __forceinline__ int ld_idx(const void* p, int i, int w64) {
    return w64 ? (int)((const i64*)p)[i] : ((const int*)p)[i];
}
__device__ __forceinline__ u16 ld_val_bf(const void* p, int i, int f32) {
    return f32 ? f2b(((const float*)p)[i]) : ((const u16*)p)[i];
}
// 4-edge vectorized loads (group g = 4 consecutive edges, 16B-aligned in both dtypes)
__device__ __forceinline__ void ld_idx4(int* r, const void* p, int g, int w64) {
    if (w64) {
        const i64* q = (const i64*)p + 4 * (size_t)g;
        longlong2 a = *(const longlong2*)q;
        longlong2 b = *(const longlong2*)(q + 2);
        r[0] = (int)a.x; r[1] = (int)a.y; r[2] = (int)b.x; r[3] = (int)b.y;
    } else {
        int4 a = *(const int4*)((const int*)p + 4 * (size_t)g);
        r[0] = a.x; r[1] = a.y; r[2] = a.z; r[3] = a.w;
    }
}
__device__ __forceinline__ void ld_val4(u32* v, const void* p, int g, int f32) {
    if (f32) {
        float4 a = *(const float4*)((const float*)p + 4 * (size_t)g);
        v[0] = f2b(a.x); v[1] = f2b(a.y); v[2] = f2b(a.z); v[3] = f2b(a.w);
    } else {
        ushort4 a = *(const ushort4*)((const u16*)p + 4 * (size_t)g);
        v[0] = a.x; v[1] = a.y; v[2] = a.z; v[3] = a.w;
    }
}

// ---------------------------------------------------------------- dtype sniff + cursor zeroing
// flags[0]=floats are fp32; flags[1]=adj_indices int64; flags[2]=feat idx int64.
__global__ void sniff_k(const u16* __restrict__ w, const u32* __restrict__ adj,
                        const u32* __restrict__ frows, int* __restrict__ flags,
                        int* __restrict__ gcurF, int* __restrict__ gcurA) {
    int t = threadIdx.x;                          // blockDim = 256
    if (t < 64) {
        u32 e0 = (w[t]      >> 7) & 0xFF;         // bf16 xavier: exp <= 0x7B always
        u32 e1 = (w[64 + t] >> 7) & 0xFF;
        u64 bad = __ballot((e0 > 0x7B) || (e1 > 0x7B));
        u64 za = __ballot(adj[2 * t + 1] == 0u);  // int64 ids: odd words are 0
        u64 zf = __ballot(frows[2 * t + 1] == 0u);
        if (t == 0) {
            flags[0] = (bad != 0);
            flags[1] = (__popcll(za) >= 32);
            flags[2] = (__popcll(zf) >= 32);
        }
    }
    for (int i = t; i < NBKT; i += 256) { gcurF[i] = 0; gcurA[i] = 0; }
}

// ---------------------------------------------------------------- binF: 2048 edges/block, one load phase
// Each thread owns one 4-edge group: rows+cols+vals loaded vectorized up front
// (held in registers across both phases). payload = val16<<16 | rlocal7<<9 | col9.
__global__ __launch_bounds__(512, 6) void binF_k(const void* __restrict__ frows,
        const void* __restrict__ fcols, const void* __restrict__ fvals, int M,
        const int* __restrict__ flags, int* __restrict__ gcurF, u32* __restrict__ fbkt) {
    __shared__ int hist[NBKT];
    __shared__ int hbase[NBKT];
    int t = threadIdx.x;
    for (int i = t; i < NBKT; i += 512) hist[i] = 0;
    __syncthreads();
    int f64 = flags[2], f32 = flags[0];
    int start = blockIdx.x * EPB;
    int end = min(start + EPB, M);
    int g = (start >> 2) + t;
    int e0 = 4 * g;
    int r[4] = {-1, -1, -1, -1};
    int c[4]; u32 v[4];
    if (e0 + 3 < end) {                 // all three vector loads in flight together
        ld_idx4(r, frows, g, f64);
        ld_idx4(c, fcols, g, f64);
        ld_val4(v, fvals, g, f32);
    } else {
        #pragma unroll
        for (int j = 0; j < 4; ++j) if (e0 + j < end) {
            r[j] = ld_idx(frows, e0 + j, f64);
            c[j] = ld_idx(fcols, e0 + j, f64);
            v[j] = ld_val_bf(fvals, e0 + j, f32);
        }
    }
    #pragma unroll
    for (int j = 0; j < 4; ++j) if (r[j] >= 0) atomicAdd(&hist[r[j] >> 7], 1);
    __syncthreads();
    for (int i = t; i < NBKT; i += 512) {
        int h = hist[i];
        hbase[i] = h ? atomicAdd(&gcurF[i], h) : 0;    // one global atomic per (block,bucket)
        hist[i] = 0;                                    // reuse as local cursor
    }
    __syncthreads();
    #pragma unroll
    for (int j = 0; j < 4; ++j) if (r[j] >= 0) {
        int b = r[j] >> 7;
        int pos = hbase[b] + atomicAdd(&hist[b], 1);
        if (pos < CAP)                                  // overflow drops loudly, never stomps
            fbkt[(size_t)b * CAP + pos] = (v[j] << 16) | ((u32)(r[j] & 127) << 9) | (u32)c[j];
    }
}

// ---------------------------------------------------------------- fused: binA (blocks < nAb) || stage1
// binA payload = val16<<24 | rlocal7<<17 | col17. Independent of stage1 (abkt vs fbkt).
union S1Mem {
    struct { int hist[NBKT]; int hbase[NBKT]; } bin;                               // 6.3 KB
    struct { u32 csr[CAP]; int hcnt[BROWS]; int roff[BROWS + 1]; int cur[BROWS]; } s1;  // 11.3 KB
};

__global__ __launch_bounds__(512, 4) void binA_s1_k(
        const void* __restrict__ adjbase, const void* __restrict__ avals, int E, int nAb,
        const int* __restrict__ flags, int* __restrict__ gcurA, u64* __restrict__ abkt,
        const int* __restrict__ cntF, const u32* __restrict__ fbkt,
        const void* __restrict__ W, u16* __restrict__ base) {
    __shared__ S1Mem sm;
    int t = threadIdx.x;
    int f32 = flags[0];
    if ((int)blockIdx.x < nAb) {
        // ---------------- binA ----------------
        for (int i = t; i < NBKT; i += 512) sm.bin.hist[i] = 0;
        __syncthreads();
        int a64 = flags[1];
        const void* acols = a64 ? (const void*)((const i64*)adjbase + E)
                                : (const void*)((const int*)adjbase + E);
        int start = blockIdx.x * EPB;
        int end = min(start + EPB, E);
        int g = (start >> 2) + t;
        int e0 = 4 * g;
        int r[4] = {-1, -1, -1, -1};
        int c[4]; u32 v[4];
        if (e0 + 3 < end) {
            ld_idx4(r, adjbase, g, a64);
            ld_idx4(c, acols, g, a64);
            ld_val4(v, avals, g, f32);
        } else {
            #pragma unroll
            for (int j = 0; j < 4; ++j) if (e0 + j < end) {
                r[j] = ld_idx(adjbase, e0 + j, a64);
                c[j] = ld_idx(acols, e0 + j, a64);
                v[j] = ld_val_bf(avals, e0 + j, f32);
            }
        }
        #pragma unroll
        for (int j = 0; j < 4; ++j) if (r[j] >= 0) atomicAdd(&sm.bin.hist[r[j] >> 7], 1);
        __syncthreads();
        for (int i = t; i < NBKT; i += 512) {
            int h = sm.bin.hist[i];
            sm.bin.hbase[i] = h ? atomicAdd(&gcurA[i], h) : 0;
            sm.bin.hist[i] = 0;
        }
        __syncthreads();
        #pragma unroll
        for (int j = 0; j < 4; ++j) if (r[j] >= 0) {
            int b = r[j] >> 7;
            int pos = sm.bin.hbase[b] + atomicAdd(&sm.bin.hist[b], 1);
            if (pos < CAP)
                abkt[(size_t)b * CAP + pos] =
                    ((u64)v[j] << 24) | ((u64)(r[j] & 127) << 17) | (u64)(u32)c[j];
        }
        return;
    }
    // ---------------- stage1: full bucket, 8 waves, payloads register-resident ----------------
    int b = blockIdx.x - nAb;
    int n = cntF[b]; if (n > CAP) n = CAP;
    const u32* ed = fbkt + (size_t)b * CAP;
    if (t < BROWS) sm.s1.hcnt[t] = 0;
    __syncthreads();
    u32 pb[5];                                   // 5-deep: bucket read happens ONCE
    #pragma unroll
    for (int k = 0; k < 5; ++k) { int i = t + k * 512; pb[k] = (i < n) ? ed[i] : 0u; }
    #pragma unroll
    for (int k = 0; k < 5; ++k) { int i = t + k * 512; if (i < n) atomicAdd(&sm.s1.hcnt[(pb[k] >> 9) & 127], 1); }
    __syncthreads();
    if (t < 64) {                                 // 128-row scan: 2 rows/lane, wave 0 only
        int h0 = sm.s1.hcnt[2 * t], h1 = sm.s1.hcnt[2 * t + 1];
        int s = h0 + h1, v2 = s;
        #pragma unroll
        for (int off = 1; off < 64; off <<= 1) {
            int u = __shfl_up(v2, off);
            if (t >= off) v2 += u;
        }
        int excl = v2 - s;
        sm.s1.roff[2 * t] = excl;     sm.s1.roff[2 * t + 1] = excl + h0;
        sm.s1.cur[2 * t]  = excl;     sm.s1.cur[2 * t + 1]  = excl + h0;
        if (t == 63) sm.s1.roff[128] = v2;
    }
    __syncthreads();
    #pragma unroll
    for (int k = 0; k < 5; ++k) {                // rank-place from registers
        int i = t + k * 512;
        if (i < n) {
            u32 p = pb[k];
            int pos = atomicAdd(&sm.s1.cur[(p >> 9) & 127], 1);
            sm.s1.csr[pos] = p;
        }
    }
    __syncthreads();
    int wave = t >> 6, lane = t & 63, g16 = lane >> 4, l16 = lane & 15;
    #pragma unroll
    for (int set = 0; set < 4; ++set) {
        int row = set * 32 + wave * 4 + g16;     // 8 waves x 4 groups = 32 rows in parallel
        int s = sm.s1.roff[row], e = sm.s1.roff[row + 1];
        float a[8] = {0.f, 0.f, 0.f, 0.f, 0.f, 0.f, 0.f, 0.f};
        if (f32) {                                // 4-deep x 32B/lane (same bytes in flight)
            const float* Wf = (const float*)W;
            for (int j0 = s; j0 < e; j0 += 4) {
                u32 p[4]; float4 qa[4], qb[4];
                #pragma unroll
                for (int k = 0; k < 4; ++k) { int jk = j0 + k; p[k] = sm.s1.csr[jk < e ? jk : e - 1]; }
                #pragma unroll
                for (int k = 0; k < 4; ++k) {
                    const float* wp = Wf + (size_t)(p[k] & 0x1FF) * F_OUT + l16 * 8;
                    qa[k] = *(const float4*)wp;
                    qb[k] = *(const float4*)(wp + 4);
                }
                #pragma unroll
                for (int k = 0; k < 4; ++k) {
                    float v = (j0 + k < e) ? b2f((u16)(p[k] >> 16)) : 0.f;
                    a[0] += v * qa[k].x; a[1] += v * qa[k].y;
                    a[2] += v * qa[k].z; a[3] += v * qa[k].w;
                    a[4] += v * qb[k].x; a[5] += v * qb[k].y;
                    a[6] += v * qb[k].z; a[7] += v * qb[k].w;
                }
            }
        } else {                                  // 8-deep x 16B/lane gathers
            const u16* Wb = (const u16*)W;
            for (int j0 = s; j0 < e; j0 += 8) {
                u32 p[8]; uint4 q[8];
                #pragma unroll
                for (int k = 0; k < 8; ++k) { int jk = j0 + k; p[k] = sm.s1.csr[jk < e ? jk : e - 1]; }
                #pragma unroll
                for (int k = 0; k < 8; ++k)
                    q[k] = *(const uint4*)(Wb + (size_t)(p[k] & 0x1FF) * F_OUT + l16 * 8);
                #pragma unroll
                for (int k = 0; k < 8; ++k) {
                    float v = (j0 + k < e) ? b2f((u16)(p[k] >> 16)) : 0.f;
                    a[0] += v * blo(q[k].x); a[1] += v * bhi(q[k].x);
                    a[2] += v * blo(q[k].y); a[3] += v * bhi(q[k].y);
                    a[4] += v * blo(q[k].z); a[5] += v * bhi(q[k].z);
                    a[6] += v * blo(q[k].w); a[7] += v * bhi(q[k].w);
                }
            }
        }
        int gr = b * BROWS + row;
        if (gr < N_NODES) {
            uint4 o;
            o.x = (u32)f2b(a[0]) | ((u32)f2b(a[1]) << 16);
            o.y = (u32)f2b(a[2]) | ((u32)f2b(a[3]) << 16);
            o.z = (u32)f2b(a[4]) | ((u32)f2b(a[5]) << 16);
            o.w = (u32)f2b(a[6]) | ((u32)f2b(a[7]) << 16);
            *(uint4*)(base + (size_t)gr * F_OUT + l16 * 8) = o;
        }
    }
}

// ---------------------------------------------------------------- stage 2: out = A_hat @ base
__global__ __launch_bounds__(512, 4) void stage2_k(const int* __restrict__ cnt,
        const u64* __restrict__ bkts, const u16* __restrict__ base,
        const int* __restrict__ flags, void* __restrict__ out) {
    __shared__ u64 csr[CAP];                  // 20.5 KB
    __shared__ int hcnt[BROWS];
    __shared__ int roff[BROWS + 1];
    __shared__ int cur[BROWS];
    int t = threadIdx.x;
    int b = blockIdx.x;
    int n = cnt[b]; if (n > CAP) n = CAP;
    const u64* ed = bkts + (size_t)b * CAP;
    if (t < BROWS) hcnt[t] = 0;
    __syncthreads();
    u64 pb[5];
    #pragma unroll
    for (int k = 0; k < 5; ++k) { int i = t + k * 512; pb[k] = (i < n) ? ed[i] : 0ull; }
    #pragma unroll
    for (int k = 0; k < 5; ++k) { int i = t + k * 512; if (i < n) atomicAdd(&hcnt[(int)((pb[k] >> 17) & 127)], 1); }
    __syncthreads();
    if (t < 64) {
        int h0 = hcnt[2 * t], h1 = hcnt[2 * t + 1];
        int s = h0 + h1, v2 = s;
        #pragma unroll
        for (int off = 1; off < 64; off <<= 1) {
            int u = __shfl_up(v2, off);
            if (t >= off) v2 += u;
        }
        int excl = v2 - s;
        roff[2 * t] = excl;     roff[2 * t + 1] = excl + h0;
        cur[2 * t]  = excl;     cur[2 * t + 1]  = excl + h0;
        if (t == 63) roff[128] = v2;
    }
    __syncthreads();
    #pragma unroll
    for (int k = 0; k < 5; ++k) {
        int i = t + k * 512;
        if (i < n) {
            u64 p = pb[k];
            int pos = atomicAdd(&cur[(int)((p >> 17) & 127)], 1);
            csr[pos] = p;
        }
    }
    __syncthreads();
    int wave = t >> 6, lane = t & 63, g16 = lane >> 4, l16 = lane & 15;
    int f32o = flags[0];
    #pragma unroll
    for (int set = 0; set < 4; ++set) {
        int row = set * 32 + wave * 4 + g16;
        int s = roff[row], e = roff[row + 1];
        float a[8] = {0.f, 0.f, 0.f, 0.f, 0.f, 0.f, 0.f, 0.f};
        for (int j0 = s; j0 < e; j0 += 8) {      // 8-deep x 16B/lane gathers from base
            u64 p[8]; uint4 q[8];
            #pragma unroll
            for (int k = 0; k < 8; ++k) { int jk = j0 + k; p[k] = csr[jk < e ? jk : e - 1]; }
            #pragma unroll
            for (int k = 0; k < 8; ++k)
                q[k] = *(const uint4*)(base + (size_t)(u32)(p[k] & 0x1FFFF) * F_OUT + l16 * 8);
            #pragma unroll
            for (int k = 0; k < 8; ++k) {
                float v = (j0 + k < e) ? b2f((u16)(p[k] >> 24)) : 0.f;
                a[0] += v * blo(q[k].x); a[1] += v * bhi(q[k].x);
                a[2] += v * blo(q[k].y); a[3] += v * bhi(q[k].y);
                a[4] += v * blo(q[k].z); a[5] += v * bhi(q[k].z);
                a[6] += v * blo(q[k].w); a[7] += v * bhi(q[k].w);
            }
        }
        int gr = b * BROWS + row;
        if (gr < N_NODES) {
            if (f32o) {
                float* op = (float*)out + (size_t)gr * F_OUT + l16 * 8;
                float4 o0, o1;
                o0.x = a[0]; o0.y = a[1]; o0.z = a[2]; o0.w = a[3];
                o1.x = a[4]; o1.y = a[5]; o1.z = a[6]; o1.w = a[7];
                *(float4*)op = o0;
                *(float4*)(op + 4) = o1;
            } else {
                uint4 o;
                o.x = (u32)f2b(a[0]) | ((u32)f2b(a[1]) << 16);
                o.y = (u32)f2b(a[2]) | ((u32)f2b(a[3]) << 16);
                o.z = (u32)f2b(a[4]) | ((u32)f2b(a[5]) << 16);
                o.w = (u32)f2b(a[6]) | ((u32)f2b(a[7]) << 16);
                *(uint4*)((u16*)out + (size_t)gr * F_OUT + l16 * 8) = o;
            }
        }
    }
}

extern "C" void kernel_launch(void* const* d_in, const int* in_sizes, int n_in,
                              void* d_out, int out_size, void* d_ws, size_t ws_size,
                              hipStream_t stream) {
    const void* adj_idx   = d_in[0];   // [2,E]: rows then cols
    const void* adj_vals  = d_in[1];
    const void* feat_rows = d_in[2];
    const void* feat_cols = d_in[3];
    const void* feat_vals = d_in[4];
    const void* weight    = d_in[5];

    const int E = in_sizes[0] / 2;
    const int M = in_sizes[2];

    // ---- workspace layout (256B-aligned), ~50 MB ----
    char* ws = (char*)d_ws;
    size_t o = 0;
    auto alloc = [&](size_t b) { size_t r = o; o += (b + 255) & ~(size_t)255; return r; };
    int* gcurF = (int*)(ws + alloc((size_t)NBKT * 4));
    int* gcurA = (int*)(ws + alloc((size_t)NBKT * 4));
    int* flags = (int*)(ws + alloc(4 * 4));
    u32* fbkt  = (u32*)(ws + alloc((size_t)NBKT * CAP * 4)); // 8.0 MB
    u64* abkt  = (u64*)(ws + alloc((size_t)NBKT * CAP * 8)); // 16.0 MB
    u16* base  = (u16*)(ws + alloc((size_t)N_NODES * F_OUT * 2)); // 25.6 MB
    (void)ws_size;

    const int nFb = (M + EPB - 1) / EPB;   // 782
    const int nAb = (E + EPB - 1) / EPB;   // 782

    sniff_k<<<1, 256, 0, stream>>>((const u16*)weight, (const u32*)adj_idx,
                                   (const u32*)feat_rows, flags, gcurF, gcurA);
    binF_k<<<nFb, 512, 0, stream>>>(feat_rows, feat_cols, feat_vals, M,
                                    flags, gcurF, fbkt);
    binA_s1_k<<<nAb + NBKT, 512, 0, stream>>>(adj_idx, adj_vals, E, nAb,
                                              flags, gcurA, abkt,
                                              gcurF, fbkt, weight, base);
    stage2_k<<<NBKT, 512, 0, stream>>>(gcurA, abkt, base, flags, d_out);
}